// Round 7
// baseline (167.060 us; speedup 1.0000x reference)
//
#include <hip/hip_runtime.h>
#include <cmath>
#include <cstdint>

#define TSZ 1024
#define RDIV 2.5f
#define UCONST 0.83f

typedef __bf16 bf16x8 __attribute__((ext_vector_type(8)));
typedef float f32x4 __attribute__((ext_vector_type(4)));
typedef unsigned short ushortT;

__device__ __forceinline__ ushortT bf16r(float f) {
  union { float f; unsigned u; } x; x.f = f;
  unsigned r = (x.u + 0x7FFFu + ((x.u >> 16) & 1u)) >> 16;
  return (ushortT)r;
}

__device__ __forceinline__ void glds16(const void* g, void* l) {
  __builtin_amdgcn_global_load_lds(
      (const __attribute__((address_space(1))) unsigned int*)(g),
      (__attribute__((address_space(3))) unsigned int*)(l), 16, 0, 0);
}

// ============ k_cvtg: NCHW fp32 -> (NHWC bf16) + per-pixel 9-tap dots ============
// LDS [128ch][65] : all phases <=2-way bank aliasing (free).
// Also zeroes count[bid] (grid 1024 == TSZ exactly).
__global__ __launch_bounds__(256) void k_cvtg(const float* __restrict__ in,
                                              const float* __restrict__ a,
                                              ushortT* __restrict__ nb,
                                              float* __restrict__ g,
                                              int* __restrict__ count) {
  __shared__ float tile2[128][65];
  __shared__ float gpart[4][9][64];
  const int bid = blockIdx.x;
  const int n = bid >> 6, y = bid & 63;
  const int t = threadIdx.x;
  if (t == 0) count[bid] = 0;
  {
    const int chs = t >> 4, l16 = t & 15;
    const float* basep = in + ((size_t)(n * 128) << 12) + (y << 6) + (l16 << 2);
#pragma unroll
    for (int i = 0; i < 8; ++i) {
      int ch = (i << 4) + chs;
      f32x4 v = *reinterpret_cast<const f32x4*>(basep + ((size_t)ch << 12));
#pragma unroll
      for (int u = 0; u < 4; ++u) tile2[ch][(l16 << 2) + u] = v[u];
    }
  }
  __syncthreads();
  {
    const int part = __builtin_amdgcn_readfirstlane(t >> 6);
    const int x = t & 63;
    float gacc[9];
#pragma unroll
    for (int tap = 0; tap < 9; ++tap) gacc[tap] = 0.f;
    const int c0 = part << 5;
#pragma unroll
    for (int i = 0; i < 32; ++i) {
      float v = tile2[c0 + i][x];
      const float* ap = a + (c0 + i) * 9;
#pragma unroll
      for (int tap = 0; tap < 9; ++tap) gacc[tap] += v * ap[tap];
    }
#pragma unroll
    for (int tap = 0; tap < 9; ++tap) gpart[part][tap][x] = gacc[tap];
  }
  __syncthreads();
  if (t < 64) {
    const int x = t;
#pragma unroll
    for (int tap = 0; tap < 9; ++tap) {
      float s = gpart[0][tap][x] + gpart[1][tap][x] + gpart[2][tap][x] + gpart[3][tap][x];
      g[tap * 65536 + (n << 12) + (y << 6) + x] = s;
    }
  }
  {
    const int x2 = t >> 2;
    ushortT* dst = nb + (((size_t)((n << 6) + y) << 6) + x2) * 128;
#pragma unroll
    for (int j = 0; j < 4; ++j) {
      int c0 = ((t & 3) << 3) + (j << 5);
      union { ushortT us[8]; uint4 v; } pk;
#pragma unroll
      for (int u = 0; u < 8; ++u) pk.us[u] = bf16r(tile2[c0 + u][x2]);
      *reinterpret_cast<uint4*>(dst + c0) = pk.v;
    }
  }
}

// ============ k_vote3: combine shifted g-planes -> votes -> histogram ============
__global__ __launch_bounds__(256) void k_vote3(const float* __restrict__ g,
                                               const float* __restrict__ a,
                                               const float* __restrict__ bb,
                                               int* __restrict__ count) {
  __shared__ int hist[TSZ];
  const int t = threadIdx.x;
  for (int i = t; i < TSZ; i += 256) hist[i] = 0;
  __syncthreads();
  const int pix = blockIdx.x * 256 + t;
  const int n = pix >> 12, y = (pix >> 6) & 63, x = pix & 63;
  float acc = 0.f;
#pragma unroll
  for (int tap = 0; tap < 9; ++tap) {
    const int dy = tap / 3 - 1, dx = tap % 3 - 1;
    const int yy = y + dy, xx = x + dx;
    if ((unsigned)yy < 64u && (unsigned)xx < 64u)
      acc += g[tap * 65536 + (n << 12) + (yy << 6) + xx];
  }
  {
    const float* av = a + 1152;
#pragma unroll
    for (int ky = 0; ky < 3; ++ky) {
      int yy = y + ky - 1;
      if ((unsigned)yy >= 64u) continue;
#pragma unroll
      for (int kx = 0; kx < 3; ++kx) {
        int xx = x + kx - 1;
        if ((unsigned)xx >= 64u) continue;
        acc += 0.5f * av[ky * 3 + kx];
      }
    }
  }
  int v = (int)floorf((acc + bb[0]) / RDIV);
  int r = v % TSZ; if (r < 0) r = -r;
  atomicAdd(&hist[r], 1);
  __syncthreads();
  for (int i = t; i < TSZ; i += 256) {
    int h = hist[i];
    if (h) atomicAdd(&count[i], h);
  }
}

// ============ hash pipeline (fp32-exact, proven) ============
__global__ __launch_bounds__(256) void k_norm(const float* __restrict__ k,
                                              unsigned* __restrict__ scaleBits) {
  int o = blockIdx.x;
  const float* row = k + (size_t)o * 1152;
  float s = 0.f;
  for (int j = threadIdx.x; j < 1152; j += 256) { float v = row[j]; s += v * v; }
  __shared__ float red[256];
  red[threadIdx.x] = s; __syncthreads();
  for (int st = 128; st; st >>= 1) {
    if (threadIdx.x < st) red[threadIdx.x] += red[threadIdx.x + st];
    __syncthreads();
  }
  if (threadIdx.x == 0) atomicMax(scaleBits, __float_as_uint(red[0]));
}

__global__ __launch_bounds__(256) void k_hash(const float* __restrict__ k,
                                              const float* __restrict__ a,
                                              const float* __restrict__ b,
                                              const unsigned* __restrict__ scaleBits,
                                              int* __restrict__ bucket) {
  int o = blockIdx.x;
  float scale = UCONST / sqrtf(__uint_as_float(scaleBits[0]));
  const float* row = k + (size_t)o * 1152;
  float dot = 0.f, p = 0.f;
  for (int j = threadIdx.x; j < 1152; j += 256) {
    float x = row[j] * scale;
    dot += x * a[j];
    p += x * x;
  }
  __shared__ float rd[256], rp[256];
  rd[threadIdx.x] = dot; rp[threadIdx.x] = p; __syncthreads();
  for (int st = 128; st; st >>= 1) {
    if (threadIdx.x < st) { rd[threadIdx.x] += rd[threadIdx.x + st]; rp[threadIdx.x] += rp[threadIdx.x + st]; }
    __syncthreads();
  }
  if (threadIdx.x == 0) {
    float acc = rd[0];
    float pw = rp[0];
    for (int i = 0; i < 9; i++) { acc += pw * a[1152 + i]; pw = pw * pw; }
    acc += b[0];
    float h = floorf(acc / RDIV);
    int hi = (int)h;
    int r = hi % TSZ; if (r < 0) r = -r;
    bucket[o] = r;
  }
}

// ============ merged argmax + mask + weight prep (BIG path) ============
__global__ __launch_bounds__(256) void k_wprep2(const int* __restrict__ count,
                                                const int* __restrict__ bucket,
                                                const float* __restrict__ w,
                                                ushortT* __restrict__ wb,
                                                float* __restrict__ tail) {
  __shared__ int sc[256];
  __shared__ int si[256];
  const int t = threadIdx.x;
  int bc = count[t], bi = t;
#pragma unroll
  for (int j = 1; j < 4; ++j) {
    int i2 = t + j * 256;
    int c2 = count[i2];
    if (c2 > bc) { bc = c2; bi = i2; }
  }
  sc[t] = bc; si[t] = bi; __syncthreads();
  for (int st = 128; st; st >>= 1) {
    if (t < st) {
      int c2 = sc[t + st], i2 = si[t + st];
      if (c2 > sc[t] || (c2 == sc[t] && i2 < si[t])) { sc[t] = c2; si[t] = i2; }
    }
    __syncthreads();
  }
  const int idx = si[0];
  const int o = blockIdx.x;
  const int m = (bucket[o] == idx) ? 1 : 0;
  if (t == 0) {
    if (o == 0) tail[0] = (float)idx;
    tail[1 + o] = (float)m;
  }
  const float mf = m ? 1.f : 0.f;
  const float* wr = w + (size_t)o * 1152;
  ushortT* dst = wb + (size_t)o * 1152;
  for (int j = t; j < 1152; j += 256) {
    int r = j >> 7, c = j & 127;
    dst[j] = bf16r(wr[c * 9 + r] * mf);
  }
}

// ============ k_gemm4: M=65536, N=256, K=1152, 2-phase-per-tile ============
// BM=256 (4 rows), BN=256, BK=32. 512 thr = 8 waves (2M x 4N), wave tile
// 128x64. 3 LDS bufs x 32KB = 96KB (1 block/CU). Fragment-linear LDS ->
// zero bank conflicts. 3-buffer 2-ahead staging, counted vmcnt(4) gate
// folded into the trailing barrier. Each tile = 2 phases:
// {ds_read (8|4) ; 2 glds ; barrier ; lgkmcnt(0) ; setprio ; 16 MFMA ; barrier}
__global__ __launch_bounds__(512, 1) void k_gemm4(const ushortT* __restrict__ nb,
                                                  const ushortT* __restrict__ wb,
                                                  const char* __restrict__ zp,
                                                  float* __restrict__ out) {
  __shared__ __align__(16) char smem[3 * 32768];
  const int t = threadIdx.x, l = t & 63, w = t >> 6;
  const int mb = blockIdx.x;               // 256 = 16 n * 16 ygroups
  const int n = mb >> 4;
  const int y0 = (mb & 15) << 2;
  const int wm = w & 1, wn = w >> 1;
  const int lr = l & 15, lq = l >> 4;
  const char* nbN = (const char*)nb + (size_t)n * 1048576;

  // wave w stages chunks {4w..4w+3}; c<16: A frag c (16 pixels), else B frag c-16
  int cC[4], yA[4], xA[4];
  const char* bPj[4];
#pragma unroll
  for (int j = 0; j < 4; ++j) {
    int c = (w << 2) + j;
    cC[j] = c;
    int m = (c << 4) + lr;
    yA[j] = y0 + (m >> 6);
    xA[j] = m & 63;
    int orow = ((c - 16) << 4) + lr;
    bPj[j] = (const char*)wb + (size_t)orow * 2304 + (lq << 4);
  }

  auto stage2 = [&](int buf, int s, int jlo) {
    const int tap = s >> 2;
    const int d3 = (tap * 0x5556) >> 16;   // tap/3 for tap<9
    const int dy = d3 - 1, dx = tap - d3 * 3 - 1;
    const int cb = (s & 3) << 6;
    char* dstb = smem + buf * 32768;
#pragma unroll
    for (int j = jlo; j < jlo + 2; ++j) {
      const char* src;
      if (cC[j] < 16) {
        int yy = yA[j] + dy, xx = xA[j] + dx;
        bool ok = ((unsigned)yy < 64u) && ((unsigned)xx < 64u);
        src = ok ? (nbN + (((yy << 6) + xx) << 8) + cb + (lq << 4))
                 : (zp + (lq << 4));
      } else {
        src = bPj[j] + (s << 6);
      }
      glds16(src, dstb + (cC[j] << 10));
    }
  };

  f32x4 acc[8][4] = {};

  // prologue: tiles 0 and 1 fully staged
  stage2(0, 0, 0); stage2(0, 0, 2);
  stage2(1, 1, 0); stage2(1, 1, 2);
  asm volatile("s_waitcnt vmcnt(4)" ::: "memory");   // tile 0 landed
  __builtin_amdgcn_s_barrier();

  for (int tt = 0; tt < 36; ++tt) {
    const char* bufb = smem + (tt % 3) * 32768;
    const bool stg = (tt + 2) < 36;
    const int sb = (tt + 2) % 3, ss = tt + 2;
    bf16x8 bv[4], afA[4], afB[4];
    // ---- phase 0: B frags + A lower half ----
#pragma unroll
    for (int ni = 0; ni < 4; ++ni)
      bv[ni] = *reinterpret_cast<const bf16x8*>(
          bufb + 16384 + (((wn << 2) + ni) << 10) + (l << 4));
#pragma unroll
    for (int mi = 0; mi < 4; ++mi)
      afA[mi] = *reinterpret_cast<const bf16x8*>(
          bufb + (((wm << 3) + mi) << 10) + (l << 4));
    if (stg) stage2(sb, ss, 0);
    __builtin_amdgcn_s_barrier();
    asm volatile("s_waitcnt lgkmcnt(0)" ::: "memory");
    __builtin_amdgcn_sched_barrier(0);
    __builtin_amdgcn_s_setprio(1);
#pragma unroll
    for (int mi = 0; mi < 4; ++mi)
#pragma unroll
      for (int ni = 0; ni < 4; ++ni)
        acc[mi][ni] = __builtin_amdgcn_mfma_f32_16x16x32_bf16(
            afA[mi], bv[ni], acc[mi][ni], 0, 0, 0);
    __builtin_amdgcn_s_setprio(0);
    __builtin_amdgcn_s_barrier();
    // ---- phase 1: A upper half (B reused from regs) ----
#pragma unroll
    for (int mi = 0; mi < 4; ++mi)
      afB[mi] = *reinterpret_cast<const bf16x8*>(
          bufb + (((wm << 3) + 4 + mi) << 10) + (l << 4));
    if (stg) stage2(sb, ss, 2);
    __builtin_amdgcn_s_barrier();
    asm volatile("s_waitcnt lgkmcnt(0)" ::: "memory");
    __builtin_amdgcn_sched_barrier(0);
    __builtin_amdgcn_s_setprio(1);
#pragma unroll
    for (int mi = 0; mi < 4; ++mi)
#pragma unroll
      for (int ni = 0; ni < 4; ++ni)
        acc[4 + mi][ni] = __builtin_amdgcn_mfma_f32_16x16x32_bf16(
            afB[mi], bv[ni], acc[4 + mi][ni], 0, 0, 0);
    __builtin_amdgcn_s_setprio(0);
    // tile gate folded into trailing barrier (counted, never 0 mid-loop)
    if (tt < 35) asm volatile("s_waitcnt vmcnt(4)" ::: "memory");
    else         asm volatile("s_waitcnt vmcnt(0)" ::: "memory");
    __builtin_amdgcn_s_barrier();
  }

  // epilogue: col o = wn*64+ni*16+lr, row m = wm*128+mi*16+lq*4+reg (contig x)
  const int pos0 = (mb & 15) << 8;
#pragma unroll
  for (int ni = 0; ni < 4; ++ni) {
    const int o = (wn << 6) + (ni << 4) + lr;
    float* op = out + ((size_t)((n << 8) + o) << 12) + pos0 + (wm << 7) + (lq << 2);
#pragma unroll
    for (int mi = 0; mi < 8; ++mi)
      *reinterpret_cast<f32x4*>(op + (mi << 4)) = acc[mi][ni];
  }
}

// ============ SMALL-tier fallback kernels (known-good) ============
__global__ __launch_bounds__(256) void k_vote2(const float* __restrict__ in,
                                               const float* __restrict__ a,
                                               const float* __restrict__ bb,
                                               int* __restrict__ count) {
  __shared__ float sb[6][8][64];
  __shared__ int hist[TSZ];
  const int t = threadIdx.x;
  for (int i = t; i < TSZ; i += 256) hist[i] = 0;
  const int bid = blockIdx.x;
  const int n = bid >> 4, y0 = (bid & 15) << 2;
  const int x = t & 63, ry = t >> 6;
  const int yq = y0 + ry;
  float acc = 0.f;
  const float* base = in + (size_t)n * 524288;
  for (int cc = 0; cc < 16; ++cc) {
    __syncthreads();
#pragma unroll
    for (int k = 0; k < 12; ++k) {
      int i = k * 256 + t;
      int row = i >> 9;
      int c8 = (i >> 6) & 7;
      int xx = i & 63;
      int yy = y0 - 1 + row;
      float v = 0.f;
      if ((unsigned)yy < 64u) v = base[(size_t)(cc * 8 + c8) * 4096 + yy * 64 + xx];
      sb[row][c8][xx] = v;
    }
    __syncthreads();
#pragma unroll
    for (int c8 = 0; c8 < 8; ++c8) {
      const float* av = a + (cc * 8 + c8) * 9;
#pragma unroll
      for (int ky = 0; ky < 3; ++ky) {
        const float* rowp = sb[ry + ky][c8];
        float left  = (x >= 1)  ? rowp[x - 1] : 0.f;
        float mid   = rowp[x];
        float right = (x <= 62) ? rowp[x + 1] : 0.f;
        acc += left * av[ky * 3 + 0] + mid * av[ky * 3 + 1] + right * av[ky * 3 + 2];
      }
    }
  }
  {
    const float* av = a + 1152;
#pragma unroll
    for (int ky = 0; ky < 3; ++ky) {
      int yy = yq + ky - 1;
      if ((unsigned)yy >= 64u) continue;
#pragma unroll
      for (int kx = 0; kx < 3; ++kx) {
        int xx = x + kx - 1;
        if ((unsigned)xx >= 64u) continue;
        acc += 0.5f * av[ky * 3 + kx];
      }
    }
  }
  int v = (int)floorf((acc + bb[0]) / RDIV);
  int r = v % TSZ; if (r < 0) r = -r;
  atomicAdd(&hist[r], 1);
  __syncthreads();
  for (int i = t; i < TSZ; i += 256) {
    int h = hist[i];
    if (h) atomicAdd(&count[i], h);
  }
}

__global__ __launch_bounds__(1024) void k_argmax(const int* __restrict__ count,
                                                 const int* __restrict__ bucket,
                                                 int* __restrict__ maskI,
                                                 float* __restrict__ tail) {
  __shared__ int sc[1024];
  __shared__ int si[1024];
  int t = threadIdx.x;
  sc[t] = count[t]; si[t] = t; __syncthreads();
  for (int st = 512; st; st >>= 1) {
    if (t < st) {
      int c2 = sc[t + st], i2 = si[t + st];
      if (c2 > sc[t] || (c2 == sc[t] && i2 < si[t])) { sc[t] = c2; si[t] = i2; }
    }
    __syncthreads();
  }
  int idx = si[0];
  if (t == 0) tail[0] = (float)idx;
  if (t < 256) {
    int m = (bucket[t] == idx) ? 1 : 0;
    maskI[t] = m;
    tail[1 + t] = (float)m;
  }
}

__global__ __launch_bounds__(256) void k_conv(const float* __restrict__ in,
                                              const float* __restrict__ w,
                                              const int* __restrict__ maskI,
                                              float* __restrict__ out) {
  const int og = blockIdx.x, n = blockIdx.y, yt = blockIdx.z;
  const int tid = threadIdx.x;
  const int tx = tid & 63, trow = tid >> 6;
  const int y0 = yt * 4;
  const int oc0 = og * 4;
  const int m0 = maskI[oc0], m1 = maskI[oc0 + 1], m2 = maskI[oc0 + 2], m3 = maskI[oc0 + 3];
  float* op = out + ((size_t)(n * 256 + oc0)) * 4096 + (size_t)(y0 + trow) * 64 + tx;
  if (!(m0 | m1 | m2 | m3)) {
    op[0] = 0.f; op[4096] = 0.f; op[8192] = 0.f; op[12288] = 0.f;
    return;
  }
  __shared__ float tile[6 * 66];
  const float* base = in + (size_t)n * 128 * 4096;
  const float* wb = w + (size_t)oc0 * 1152;
  float a0 = 0.f, a1 = 0.f, a2 = 0.f, a3 = 0.f;
  for (int c = 0; c < 128; c++) {
    __syncthreads();
    for (int i = tid; i < 396; i += 256) {
      int r = i / 66, col = i - r * 66;
      int yy = y0 - 1 + r, xx = col - 1;
      float v = 0.f;
      if ((unsigned)yy < 64u && (unsigned)xx < 64u) v = base[(size_t)c * 4096 + yy * 64 + xx];
      tile[i] = v;
    }
    __syncthreads();
    const int ro = trow * 66 + tx;
    float t00 = tile[ro],        t01 = tile[ro + 1],   t02 = tile[ro + 2];
    float t10 = tile[ro + 66],   t11 = tile[ro + 67],  t12 = tile[ro + 68];
    float t20 = tile[ro + 132],  t21 = tile[ro + 133], t22 = tile[ro + 134];
    const float* wc = wb + c * 9;
    if (m0) { const float* q = wc;        a0 += t00*q[0]+t01*q[1]+t02*q[2]+t10*q[3]+t11*q[4]+t12*q[5]+t20*q[6]+t21*q[7]+t22*q[8]; }
    if (m1) { const float* q = wc + 1152; a1 += t00*q[0]+t01*q[1]+t02*q[2]+t10*q[3]+t11*q[4]+t12*q[5]+t20*q[6]+t21*q[7]+t22*q[8]; }
    if (m2) { const float* q = wc + 2304; a2 += t00*q[0]+t01*q[1]+t02*q[2]+t10*q[3]+t11*q[4]+t12*q[5]+t20*q[6]+t21*q[7]+t22*q[8]; }
    if (m3) { const float* q = wc + 3456; a3 += t00*q[0]+t01*q[1]+t02*q[2]+t10*q[3]+t11*q[4]+t12*q[5]+t20*q[6]+t21*q[7]+t22*q[8]; }
  }
  op[0]     = m0 ? a0 : 0.f;
  op[4096]  = m1 ? a1 : 0.f;
  op[8192]  = m2 ? a2 : 0.f;
  op[12288] = m3 ? a3 : 0.f;
}

extern "C" void kernel_launch(void* const* d_in, const int* in_sizes, int n_in,
                              void* d_out, int out_size, void* d_ws, size_t ws_size,
                              hipStream_t stream) {
  const float* in = (const float*)d_in[0];   // [16,128,64,64]
  const float* kw = (const float*)d_in[1];   // [256,128,3,3]
  const float* a  = (const float*)d_in[2];   // [1161]
  const float* b  = (const float*)d_in[3];   // [1]
  float* out = (float*)d_out;                // 16777216 + 1 + 256 floats

  char* ws = (char*)d_ws;
  const size_t NEED_BIG = 19731776ULL;

  if (ws_size >= NEED_BIG) {
    // -------- fast path --------
    ushortT* nb   = (ushortT*)(ws);                 // 16,777,216 B NHWC bf16
    ushortT* wb   = (ushortT*)(ws + 16777216);      // 589,824 B
    float* g      = (float*)(ws + 17367040);        // 2,359,296 B (9 planes)
    int* count    = (int*)(ws + 19726336);          // 4096 (zeroed by k_cvtg)
    unsigned* scB = (unsigned*)(ws + 19730432);     // 64
    char* zpage   = (ws + 19730496);                // 256
    int* bucket   = (int*)(ws + 19730752);          // 1024

    hipMemsetAsync(ws + 19730432, 0, 320, stream);  // scB + zpage only

    k_cvtg<<<1024, 256, 0, stream>>>(in, a, nb, g, count);
    k_norm<<<256, 256, 0, stream>>>(kw, scB);
    k_hash<<<256, 256, 0, stream>>>(kw, a, b, scB, bucket);
    k_vote3<<<256, 256, 0, stream>>>(g, a, b, count);
    k_wprep2<<<256, 256, 0, stream>>>(count, bucket, kw, wb, out + 16777216);
    k_gemm4<<<256, 512, 0, stream>>>(nb, wb, zpage, out);
  } else {
    // -------- fallback: direct conv path --------
    int* count    = (int*)(ws);                     // 4096
    unsigned* scB = (unsigned*)(ws + 4096);         // 64
    int* bucket   = (int*)(ws + 4160);              // 1024
    int* maskI    = (int*)(ws + 5184);              // 1024

    hipMemsetAsync(ws, 0, 4160, stream);
    k_norm<<<256, 256, 0, stream>>>(kw, scB);
    k_hash<<<256, 256, 0, stream>>>(kw, a, b, scB, bucket);
    k_vote2<<<256, 256, 0, stream>>>(in, a, b, count);
    k_argmax<<<1, 1024, 0, stream>>>(count, bucket, maskI, out + 16777216);
    dim3 grid(64, 16, 16);
    k_conv<<<grid, 256, 0, stream>>>(in, kw, maskI, out);
  }
}